// Round 4
// baseline (146.636 us; speedup 1.0000x reference)
//
#include <hip/hip_runtime.h>
#include <hip/hip_bf16.h>
#include <cstdint>

typedef __attribute__((ext_vector_type(8))) short v8s;   // 8 x bf16 bits (4 VGPRs)
typedef __attribute__((ext_vector_type(4))) float v4f;   // 16B fp32 / MFMA acc

#define NUM_HEADS 8
#define D 256
#define CCH 2048               // channels
#define SEGS_PER_HEAD 224      // 224 segs x 7 tiles = 1568 tiles/head
#define TILES_PER_SEG 7

// float -> bf16 bits, round-to-nearest-even
__device__ __forceinline__ short f2bf(float f) {
  unsigned u = __builtin_bit_cast(unsigned, f);
  u = (u + 0x7FFFu + ((u >> 16) & 1u)) >> 16;
  return (short)u;
}

// ---------------------------------------------------------------------------
// Pack weight (8,256,256) fp32 -> fragment-ordered bf16 in d_ws (1 MiB).
// Unit u = (s*16 + j)*64 + lane within head, 16 B each:
// B[k = s*32 + (lane>>4)*8 + e][n = j*16 + (lane&15)], e = 0..7 — the
// mfma_f32_16x16x32_bf16 B fragment for (kstep s, ntile j).
// ---------------------------------------------------------------------------
__global__ __launch_bounds__(256) void pack_w(const float* __restrict__ w,
                                              short* __restrict__ p) {
  int idx  = blockIdx.x * 256 + threadIdx.x;  // 0..65535
  int lane = idx & 63;
  int j    = (idx >> 6) & 15;
  int s    = (idx >> 10) & 7;
  int head = idx >> 13;
  int n  = j * 16 + (lane & 15);
  int k0 = s * 32 + (lane >> 4) * 8;
  const float* src = w + head * 65536 + k0 * 256 + n;
  v8s v;
#pragma unroll
  for (int e = 0; e < 8; ++e) v[e] = f2bf(src[e * 256]);
  *reinterpret_cast<v8s*>(p + (size_t)idx * 8) = v;
}

// ---------------------------------------------------------------------------
// Main grouped GEMM — barrier-free, LDS-free streaming.
// 1792 blocks x 256 threads (4 waves). Block = (head, 7-tile segment).
// Wave wv owns ntiles j = wv*4 .. wv*4+3: its B slice is register-resident
// (32 fragments = 128 VGPR), loaded once from the packed (L3-resident) buffer.
// Per tile: 16 independent dwordx4 A loads (fragment-direct; lo/hi pairs are
// line-adjacent so L1 merges them; the 4 waves' duplicate A reads hit L1/L2),
// f2bf convert, 32 MFMA (4 independent acc chains), 16 dword stores.
// No __syncthreads, no LDS: latency is hidden by 16-deep load ILP + 8 waves/CU.
// ---------------------------------------------------------------------------
__global__ __launch_bounds__(256, 2) void grouped_mm(const float* __restrict__ x,
                                                     const short* __restrict__ pB,
                                                     float* __restrict__ out) {
  const int tid  = threadIdx.x;
  const int wv   = tid >> 6;          // wave 0..3 -> ntiles wv*4..wv*4+3
  const int lane = tid & 63;
  const int head = blockIdx.x / SEGS_PER_HEAD;
  const int seg  = blockIdx.x % SEGS_PER_HEAD;
  const int row  = lane & 15;         // A-fragment row within tile
  const int kg   = lane >> 4;         // k subgroup

  // ---- persistent B fragments: 8 ksteps x 4 ntiles, 16B/lane each ----
  v8s Bf[8][4];
  {
    const short* pb = pB + (size_t)head * 65536 + (size_t)lane * 8;
#pragma unroll
    for (int s = 0; s < 8; ++s) {
#pragma unroll
      for (int jj = 0; jj < 4; ++jj) {
        Bf[s][jj] = *reinterpret_cast<const v8s*>(pb + (size_t)(s * 16 + wv * 4 + jj) * 512);
      }
    }
  }

  const int t0 = seg * TILES_PER_SEG;  // head-local tile index
  for (int t = t0; t < t0 + TILES_PER_SEG; ++t) {
    // ---- A fragment loads: 16 independent dwordx4 ----
    const float* ap = x + (size_t)(t * 16 + row) * CCH + head * D + kg * 8;
    v4f a[8][2];
#pragma unroll
    for (int s = 0; s < 8; ++s) {
      a[s][0] = *reinterpret_cast<const v4f*>(ap + s * 32);
      a[s][1] = *reinterpret_cast<const v4f*>(ap + s * 32 + 4);
    }

    v4f acc[4];
#pragma unroll
    for (int jj = 0; jj < 4; ++jj) acc[jj] = (v4f){0.f, 0.f, 0.f, 0.f};

#pragma unroll
    for (int s = 0; s < 8; ++s) {
      v8s af;
#pragma unroll
      for (int e = 0; e < 4; ++e) {
        af[e]     = f2bf(a[s][0][e]);
        af[4 + e] = f2bf(a[s][1][e]);
      }
#pragma unroll
      for (int jj = 0; jj < 4; ++jj) {
        acc[jj] = __builtin_amdgcn_mfma_f32_16x16x32_bf16(af, Bf[s][jj], acc[jj], 0, 0, 0);
      }
    }

    // C/D layout: col = lane&15, row = kg*4 + r
    float* op = out + (size_t)(t * 16 + kg * 4) * CCH + head * D + wv * 64 + row;
#pragma unroll
    for (int jj = 0; jj < 4; ++jj) {
#pragma unroll
      for (int r = 0; r < 4; ++r) {
        op[(size_t)r * CCH + jj * 16] = acc[jj][r];
      }
    }
  }
}

extern "C" void kernel_launch(void* const* d_in, const int* in_sizes, int n_in,
                              void* d_out, int out_size, void* d_ws, size_t ws_size,
                              hipStream_t stream) {
  const float* x = (const float*)d_in[0];   // (8,56,56,2048) fp32
  const float* w = (const float*)d_in[1];   // (8,256,256) fp32
  float* out = (float*)d_out;               // (8,56,56,2048) fp32
  short* packed = (short*)d_ws;             // 1 MiB packed bf16 weights

  pack_w<<<256, 256, 0, stream>>>(w, packed);
  grouped_mm<<<NUM_HEADS * SEGS_PER_HEAD, 256, 0, stream>>>(x, packed, out);
}

// Round 5
// 89.380 us; speedup vs baseline: 1.6406x; 1.6406x over previous
//
#include <hip/hip_runtime.h>
#include <hip/hip_bf16.h>
#include <cstdint>

typedef __attribute__((ext_vector_type(8))) short v8s;   // 8 x bf16 bits (4 VGPRs)
typedef __attribute__((ext_vector_type(4))) float v4f;   // 16B fp32 / MFMA acc

#define NUM_HEADS 8
#define D 256
#define CCH 2048               // channels
#define SEGS 64                // segments (blocks) per head
#define TILES_PER_HEAD 1568    // 25088 tokens / 16

// float -> bf16 bits, round-to-nearest-even
__device__ __forceinline__ short f2bf(float f) {
  unsigned u = __builtin_bit_cast(unsigned, f);
  u = (u + 0x7FFFu + ((u >> 16) & 1u)) >> 16;
  return (short)u;
}

// ---------------------------------------------------------------------------
// Pack weight (8,256,256) fp32 -> fragment-ordered bf16 in d_ws (1 MiB).
// Unit u = (s*16 + j)*64 + lane within head, 16 B each:
// B[k = s*32 + (lane>>4)*8 + e][n = j*16 + (lane&15)], e = 0..7 — the
// mfma_f32_16x16x32_bf16 B fragment for (kstep s, ntile j).
// ---------------------------------------------------------------------------
__global__ __launch_bounds__(256) void pack_w(const float* __restrict__ w,
                                              short* __restrict__ p) {
  int idx  = blockIdx.x * 256 + threadIdx.x;  // 0..65535
  int lane = idx & 63;
  int j    = (idx >> 6) & 15;
  int s    = (idx >> 10) & 7;
  int head = idx >> 13;
  int n  = j * 16 + (lane & 15);
  int k0 = s * 32 + (lane >> 4) * 8;
  const float* src = w + head * 65536 + k0 * 256 + n;
  v8s v;
#pragma unroll
  for (int e = 0; e < 8; ++e) v[e] = f2bf(src[e * 256]);
  *reinterpret_cast<v8s*>(p + (size_t)idx * 8) = v;
}

typedef __attribute__((address_space(1))) const unsigned int GAS;
typedef __attribute__((address_space(3))) unsigned int LAS;

// ---------------------------------------------------------------------------
// Main grouped GEMM. 512 blocks (2/CU) x 512 threads (8 waves) = 4 waves/SIMD.
// Block = (head, 24/25-tile segment). Two independent barrier domains per CU:
// while one block drains vmcnt at its __syncthreads, the sibling block keeps
// issuing — removes the round-3 CU-wide lockstep tax.
// B: register-resident 2 ntiles x 8 ksteps per wave (64 VGPR), loaded once.
// A: double-buffered LDS (2 x 16 KB), staged row-contiguous via
//    global_load_lds (1 KB/instruction) with XOR-pre-swizzled global source;
//    ds_read_b128 with the same XOR -> max 2-way bank aliasing (free).
// 1 tile per period, 1 barrier per period.
// ---------------------------------------------------------------------------
__global__ __launch_bounds__(512, 4) void grouped_mm(const float* __restrict__ x,
                                                     const short* __restrict__ pB,
                                                     float* __restrict__ out) {
  __shared__ alignas(16) char As[2][16384];  // [slot][row16][1024B]
  const int tid  = threadIdx.x;
  const int wv   = tid >> 6;          // wave 0..7 = n-group (ntiles 2wv, 2wv+1)
  const int lane = tid & 63;
  const int head = blockIdx.x >> 6;
  const int seg  = blockIdx.x & 63;
  const int t0   = (seg < 32) ? seg * 25 : 800 + (seg - 32) * 24;
  const int nt   = (seg < 32) ? 25 : 24;

  const int arow = lane & 15;         // A-fragment row
  const int kg   = lane >> 4;         // k subgroup

  // ---- persistent B fragments: 2 ntiles x 8 ksteps (64 VGPR) ----
  v8s Bf0[8], Bf1[8];
  {
    const short* pb = pB + (size_t)head * 65536 + (size_t)lane * 8;
#pragma unroll
    for (int s = 0; s < 8; ++s) {
      Bf0[s] = *reinterpret_cast<const v8s*>(pb + (size_t)(s * 16 + 2 * wv)     * 512);
      Bf1[s] = *reinterpret_cast<const v8s*>(pb + (size_t)(s * 16 + 2 * wv + 1) * 512);
    }
  }

  const char* xbase = (const char*)(x + (size_t)head * D);

  // wave stages rows 2wv, 2wv+1 of head-local tile t (global token tile t)
  auto stage = [&](int slot, int t) {
#pragma unroll
    for (int q = 0; q < 2; ++q) {
      const int r = 2 * wv + q;
      const unsigned lsw = ((unsigned)(lane * 16)) ^ (unsigned)((r & 7) << 4);
      const char* g = xbase + ((size_t)(t * 16 + r)) * (CCH * 4) + lsw;
      char* l = As[slot] + r * 1024;
      __builtin_amdgcn_global_load_lds((GAS*)g, (LAS*)l, 16, 0, 0);
    }
  };

  stage(0, t0);
  __syncthreads();  // drains vmcnt

  const unsigned rswz = (unsigned)((arow & 7) << 4);

  for (int p = 0; p < nt; ++p) {
    const int cur = p & 1;

    // issue next tile's staging first (hides under this period's compute)
    if (p + 1 < nt) stage(cur ^ 1, t0 + p + 1);

    const char* ar = As[cur] + arow * 1024;
    v4f acc0 = (v4f){0.f, 0.f, 0.f, 0.f};
    v4f acc1 = (v4f){0.f, 0.f, 0.f, 0.f};
#pragma unroll
    for (int s = 0; s < 8; ++s) {
      const unsigned q0 = ((unsigned)(s * 128 + kg * 32)) ^ rswz;
      v4f lo = *reinterpret_cast<const v4f*>(ar + q0);
      v4f hi = *reinterpret_cast<const v4f*>(ar + (q0 ^ 16u));
      v8s af;
#pragma unroll
      for (int e = 0; e < 4; ++e) {
        af[e]     = f2bf(lo[e]);
        af[4 + e] = f2bf(hi[e]);
      }
      acc0 = __builtin_amdgcn_mfma_f32_16x16x32_bf16(af, Bf0[s], acc0, 0, 0, 0);
      acc1 = __builtin_amdgcn_mfma_f32_16x16x32_bf16(af, Bf1[s], acc1, 0, 0, 0);
    }

    // C/D layout: col = lane&15, row = kg*4 + r
    float* op = out + (size_t)((t0 + p) * 16 + kg * 4) * CCH
                    + head * D + wv * 32 + arow;
#pragma unroll
    for (int r = 0; r < 4; ++r) {
      op[(size_t)r * CCH]      = acc0[r];
      op[(size_t)r * CCH + 16] = acc1[r];
    }
    __syncthreads();
  }
}

extern "C" void kernel_launch(void* const* d_in, const int* in_sizes, int n_in,
                              void* d_out, int out_size, void* d_ws, size_t ws_size,
                              hipStream_t stream) {
  const float* x = (const float*)d_in[0];   // (8,56,56,2048) fp32
  const float* w = (const float*)d_in[1];   // (8,256,256) fp32
  float* out = (float*)d_out;               // (8,56,56,2048) fp32
  short* packed = (short*)d_ws;             // 1 MiB packed bf16 weights

  pack_w<<<256, 256, 0, stream>>>(w, packed);
  grouped_mm<<<NUM_HEADS * SEGS, 512, 0, stream>>>(x, packed, out);
}

// Round 6
// 89.155 us; speedup vs baseline: 1.6447x; 1.0025x over previous
//
#include <hip/hip_runtime.h>
#include <hip/hip_bf16.h>
#include <cstdint>

typedef __attribute__((ext_vector_type(8))) short v8s;   // 8 x bf16 bits (4 VGPRs)
typedef __attribute__((ext_vector_type(4))) float v4f;   // 16B fp32 / MFMA acc

#define NUM_HEADS 8
#define D 256
#define CCH 2048               // channels
#define SEGS 64                // segments (blocks) per head

// float -> bf16 bits, round-to-nearest-even
__device__ __forceinline__ short f2bf(float f) {
  unsigned u = __builtin_bit_cast(unsigned, f);
  u = (u + 0x7FFFu + ((u >> 16) & 1u)) >> 16;
  return (short)u;
}

// ---------------------------------------------------------------------------
// Pack weight (8,256,256) fp32 -> fragment-ordered bf16 in d_ws (1 MiB).
// Unit u = (s*16 + j)*64 + lane within head, 16 B each:
// B[k = s*32 + (lane>>4)*8 + e][n = j*16 + (lane&15)], e = 0..7 — the
// mfma_f32_16x16x32_bf16 B fragment for (kstep s, ntile j).
// ---------------------------------------------------------------------------
__global__ __launch_bounds__(256) void pack_w(const float* __restrict__ w,
                                              short* __restrict__ p) {
  int idx  = blockIdx.x * 256 + threadIdx.x;  // 0..65535
  int lane = idx & 63;
  int j    = (idx >> 6) & 15;
  int s    = (idx >> 10) & 7;
  int head = idx >> 13;
  int n  = j * 16 + (lane & 15);
  int k0 = s * 32 + (lane >> 4) * 8;
  const float* src = w + head * 65536 + k0 * 256 + n;
  v8s v;
#pragma unroll
  for (int e = 0; e < 8; ++e) v[e] = f2bf(src[e * 256]);
  *reinterpret_cast<v8s*>(p + (size_t)idx * 8) = v;
}

typedef __attribute__((address_space(1))) const unsigned int GAS;
typedef __attribute__((address_space(3))) unsigned int LAS;

// ---------------------------------------------------------------------------
// Main grouped GEMM. 512 blocks (2/CU) x 512 threads (8 waves) = 4 waves/SIMD.
// Block = (head, 24/25-tile segment). Wave wv owns ntiles {2wv, 2wv+1}; its B
// slice is register-resident (64 VGPR), loaded once.
// A: ring-3 LDS (3 x 16 KB). Period p stages tile p+2 (row-contiguous
//    global_load_lds, XOR-swizzled on BOTH the pre-swizzled global source and
//    the ds_read address), consumes tile p. Sync = counted vmcnt + raw
//    s_barrier: newest 10 VMEM ops per wave at the barrier are
//    stage(p+2)[2] + stores(p)[8], so vmcnt(10) guarantees stage(p+1) and
//    stores(p-1) retired while the next-next stage stays in flight across the
//    barrier (never vmcnt(0) in the loop).
// Slot-overwrite race check: slot (p+2)%3 was last read in period p-1; the
// period-(p-1) barrier orders those reads before this stage. 1 barrier/period.
// ---------------------------------------------------------------------------
__global__ __launch_bounds__(512, 4) void grouped_mm(const float* __restrict__ x,
                                                     const short* __restrict__ pB,
                                                     float* __restrict__ out) {
  __shared__ alignas(16) char As[3][16384];  // ring: [slot][row16][1024B]
  const int tid  = threadIdx.x;
  const int wv   = tid >> 6;          // wave 0..7 = n-group (ntiles 2wv, 2wv+1)
  const int lane = tid & 63;
  const int head = blockIdx.x >> 6;
  const int seg  = blockIdx.x & 63;
  const int t0   = (seg < 32) ? seg * 25 : 800 + (seg - 32) * 24;
  const int nt   = (seg < 32) ? 25 : 24;

  const int arow = lane & 15;         // A-fragment row
  const int kg   = lane >> 4;         // k subgroup

  // ---- persistent B fragments: 2 ntiles x 8 ksteps (64 VGPR) ----
  v8s Bf0[8], Bf1[8];
  {
    const short* pb = pB + (size_t)head * 65536 + (size_t)lane * 8;
#pragma unroll
    for (int s = 0; s < 8; ++s) {
      Bf0[s] = *reinterpret_cast<const v8s*>(pb + (size_t)(s * 16 + 2 * wv)     * 512);
      Bf1[s] = *reinterpret_cast<const v8s*>(pb + (size_t)(s * 16 + 2 * wv + 1) * 512);
    }
  }

  const char* xbase = (const char*)(x + (size_t)head * D);

  // wave stages rows 2wv, 2wv+1 of head-local tile t into ring slot
  auto stage = [&](int slot, int t) {
#pragma unroll
    for (int q = 0; q < 2; ++q) {
      const int r = 2 * wv + q;
      const unsigned lsw = ((unsigned)(lane * 16)) ^ (unsigned)((r & 7) << 4);
      const char* g = xbase + ((size_t)(t * 16 + r)) * (CCH * 4) + lsw;
      char* l = &As[0][0] + slot * 16384 + r * 1024;
      __builtin_amdgcn_global_load_lds((GAS*)g, (LAS*)l, 16, 0, 0);
    }
  };

  // prologue: fill 2 ring slots, wait only for slot 0
  stage(0, t0);
  stage(1, t0 + 1);
  asm volatile("s_waitcnt vmcnt(2)" ::: "memory");
  __builtin_amdgcn_s_barrier();

  const unsigned rswz = (unsigned)((arow & 7) << 4);
  int cur = 0;

  for (int p = 0; p < nt; ++p) {
    // stage tile p+2 into slot (cur+2)%3 (spans this period + next barrier)
    int nslot = cur + 2; if (nslot >= 3) nslot -= 3;
    if (p + 2 < nt) stage(nslot, t0 + p + 2);

    const char* ar = &As[0][0] + cur * 16384 + arow * 1024;
    v4f acc0 = (v4f){0.f, 0.f, 0.f, 0.f};
    v4f acc1 = (v4f){0.f, 0.f, 0.f, 0.f};
#pragma unroll
    for (int s = 0; s < 8; ++s) {
      const unsigned q0 = ((unsigned)(s * 128 + kg * 32)) ^ rswz;
      v4f lo = *reinterpret_cast<const v4f*>(ar + q0);
      v4f hi = *reinterpret_cast<const v4f*>(ar + (q0 ^ 16u));
      v8s af;
#pragma unroll
      for (int e = 0; e < 4; ++e) {
        af[e]     = f2bf(lo[e]);
        af[4 + e] = f2bf(hi[e]);
      }
      acc0 = __builtin_amdgcn_mfma_f32_16x16x32_bf16(af, Bf0[s], acc0, 0, 0, 0);
      acc1 = __builtin_amdgcn_mfma_f32_16x16x32_bf16(af, Bf1[s], acc1, 0, 0, 0);
    }

    // C/D layout: col = lane&15, row = kg*4 + r  (8 stores per wave)
    float* op = out + (size_t)((t0 + p) * 16 + kg * 4) * CCH
                    + head * D + wv * 32 + arow;
#pragma unroll
    for (int r = 0; r < 4; ++r) {
      op[(size_t)r * CCH]      = acc0[r];
      op[(size_t)r * CCH + 16] = acc1[r];
    }

    // newest 10 VMEM ops = stage(p+2)[2] + stores(p)[8]  ->  this wait
    // guarantees stage(p+1) + stores(p-1) retired, keeps stage(p+2) in flight
    asm volatile("s_waitcnt vmcnt(10)" ::: "memory");
    __builtin_amdgcn_s_barrier();

    cur = cur + 1; if (cur >= 3) cur = 0;
  }
}

extern "C" void kernel_launch(void* const* d_in, const int* in_sizes, int n_in,
                              void* d_out, int out_size, void* d_ws, size_t ws_size,
                              hipStream_t stream) {
  const float* x = (const float*)d_in[0];   // (8,56,56,2048) fp32
  const float* w = (const float*)d_in[1];   // (8,256,256) fp32
  float* out = (float*)d_out;               // (8,56,56,2048) fp32
  short* packed = (short*)d_ws;             // 1 MiB packed bf16 weights

  pack_w<<<256, 256, 0, stream>>>(w, packed);
  grouped_mm<<<NUM_HEADS * SEGS, 512, 0, stream>>>(x, packed, out);
}

// Round 8
// 88.794 us; speedup vs baseline: 1.6514x; 1.0041x over previous
//
#include <hip/hip_runtime.h>
#include <hip/hip_bf16.h>
#include <cstdint>

typedef __attribute__((ext_vector_type(8))) short v8s;   // 8 x bf16 bits (4 VGPRs)
typedef __attribute__((ext_vector_type(4))) float v4f;   // 16B fp32 / MFMA acc

#define NUM_HEADS 8
#define D 256
#define CCH 2048               // channels
#define SEGS 64                // segments (blocks) per head

// float -> bf16 bits, round-to-nearest-even
__device__ __forceinline__ short f2bf(float f) {
  unsigned u = __builtin_bit_cast(unsigned, f);
  u = (u + 0x7FFFu + ((u >> 16) & 1u)) >> 16;
  return (short)u;
}

// ---------------------------------------------------------------------------
// Pack weight (8,256,256) fp32 -> fragment-ordered bf16 in d_ws (1 MiB).
// Unit u = (s*16 + j)*64 + lane within head, 16 B each:
// B[k = s*32 + (lane>>4)*8 + e][n = j*16 + (lane&15)], e = 0..7 — the
// mfma_f32_16x16x32_bf16 B fragment for (kstep s, ntile j).
// ---------------------------------------------------------------------------
__global__ __launch_bounds__(256) void pack_w(const float* __restrict__ w,
                                              short* __restrict__ p) {
  int idx  = blockIdx.x * 256 + threadIdx.x;  // 0..65535
  int lane = idx & 63;
  int j    = (idx >> 6) & 15;
  int s    = (idx >> 10) & 7;
  int head = idx >> 13;
  int n  = j * 16 + (lane & 15);
  int k0 = s * 32 + (lane >> 4) * 8;
  const float* src = w + head * 65536 + k0 * 256 + n;
  v8s v;
#pragma unroll
  for (int e = 0; e < 8; ++e) v[e] = f2bf(src[e * 256]);
  *reinterpret_cast<v8s*>(p + (size_t)idx * 8) = v;
}

typedef __attribute__((address_space(1))) const unsigned int GAS;
typedef __attribute__((address_space(3))) unsigned int LAS;

// ---------------------------------------------------------------------------
// Main grouped GEMM. 512 blocks (2/CU) x 512 threads (8 waves) = 4 waves/SIMD.
// Block = (head, 24/25-tile segment). Wave wv: ntiles {2wv,2wv+1}, B slice
// register-resident (64 VGPR), loaded once.
// A: ring-3 LDS (3 x 16 KB), stage(p+2) per period, counted vmcnt.
// Epilogue: transpose output tile through the just-consumed LDS slot; stores
// are 2 x global_store_dwordx4 (1 KB dense rows) per wave.
// Swizzle convention (rule #21, both-sides): LDS byte (col*4)^rs holds
// element col of row rowi, rs=(rowi&7)<<4. ds_write applies ^rs; the
// store-phase ds_read applies ^rs; the GLOBAL store address is LINEAR
// (lane*16) — this was round 7's bug (global side had ^rs too).
// Period: stage -> compute -> bar1 -> ds_write acc -> lgkm+bar2 ->
// ds_read rows -> dwordx4 stores -> vmcnt(4)+bar3.
// ---------------------------------------------------------------------------
__global__ __launch_bounds__(512, 4) void grouped_mm(const float* __restrict__ x,
                                                     const short* __restrict__ pB,
                                                     float* __restrict__ out) {
  __shared__ alignas(16) char As[3][16384];  // ring: [slot][row16][1024B]
  const int tid  = threadIdx.x;
  const int wv   = tid >> 6;          // wave 0..7 = n-group (ntiles 2wv, 2wv+1)
  const int lane = tid & 63;
  const int head = blockIdx.x >> 6;
  const int seg  = blockIdx.x & 63;
  const int t0   = (seg < 32) ? seg * 25 : 800 + (seg - 32) * 24;
  const int nt   = (seg < 32) ? 25 : 24;

  const int arow = lane & 15;         // A-fragment row
  const int kg   = lane >> 4;         // k subgroup

  // ---- persistent B fragments: 2 ntiles x 8 ksteps (64 VGPR) ----
  v8s Bf0[8], Bf1[8];
  {
    const short* pb = pB + (size_t)head * 65536 + (size_t)lane * 8;
#pragma unroll
    for (int s = 0; s < 8; ++s) {
      Bf0[s] = *reinterpret_cast<const v8s*>(pb + (size_t)(s * 16 + 2 * wv)     * 512);
      Bf1[s] = *reinterpret_cast<const v8s*>(pb + (size_t)(s * 16 + 2 * wv + 1) * 512);
    }
  }

  const char* xbase = (const char*)(x + (size_t)head * D);

  // wave stages rows 2wv, 2wv+1 of head-local tile t into ring slot
  auto stage = [&](int slot, int t) {
#pragma unroll
    for (int q = 0; q < 2; ++q) {
      const int r = 2 * wv + q;
      const unsigned lsw = ((unsigned)(lane * 16)) ^ (unsigned)((r & 7) << 4);
      const char* g = xbase + ((size_t)(t * 16 + r)) * (CCH * 4) + lsw;
      char* l = &As[0][0] + slot * 16384 + r * 1024;
      __builtin_amdgcn_global_load_lds((GAS*)g, (LAS*)l, 16, 0, 0);
    }
  };

  // prologue: fill 2 ring slots, wait only for slot 0
  stage(0, t0);
  stage(1, t0 + 1);
  asm volatile("s_waitcnt vmcnt(2)" ::: "memory");
  __builtin_amdgcn_s_barrier();

  const unsigned rswz = (unsigned)((arow & 7) << 4);
  int cur = 0;

  for (int p = 0; p < nt; ++p) {
    // stage tile p+2 into slot (cur+2)%3
    int nslot = cur + 2; if (nslot >= 3) nslot -= 3;
    if (p + 2 < nt) stage(nslot, t0 + p + 2);

    char* slotp = &As[0][0] + cur * 16384;
    const char* ar = slotp + arow * 1024;
    v4f acc0 = (v4f){0.f, 0.f, 0.f, 0.f};
    v4f acc1 = (v4f){0.f, 0.f, 0.f, 0.f};
#pragma unroll
    for (int s = 0; s < 8; ++s) {
      const unsigned q0 = ((unsigned)(s * 128 + kg * 32)) ^ rswz;
      v4f lo = *reinterpret_cast<const v4f*>(ar + q0);
      v4f hi = *reinterpret_cast<const v4f*>(ar + (q0 ^ 16u));
      v8s af;
#pragma unroll
      for (int e = 0; e < 4; ++e) {
        af[e]     = f2bf(lo[e]);
        af[4 + e] = f2bf(hi[e]);
      }
      acc0 = __builtin_amdgcn_mfma_f32_16x16x32_bf16(af, Bf0[s], acc0, 0, 0, 0);
      acc1 = __builtin_amdgcn_mfma_f32_16x16x32_bf16(af, Bf1[s], acc1, 0, 0, 0);
    }

    // ---- all waves done reading slot cur ----
    __builtin_amdgcn_s_barrier();

    // ---- transpose through slot cur: acc -> LDS (element col at (col*4)^rs)
    // C/D layout: lane holds (row = kg*4 + r, col = lane&15) of each ntile.
#pragma unroll
    for (int r = 0; r < 4; ++r) {
      const int rowi = kg * 4 + r;
      const unsigned rs = (unsigned)((rowi & 7) << 4);
      unsigned c0 = ((unsigned)((wv * 32      + arow) * 4)) ^ rs;
      unsigned c1 = ((unsigned)((wv * 32 + 16 + arow) * 4)) ^ rs;
      *reinterpret_cast<float*>(slotp + rowi * 1024 + c0) = acc0[r];
      *reinterpret_cast<float*>(slotp + rowi * 1024 + c1) = acc1[r];
    }
    asm volatile("s_waitcnt lgkmcnt(0)" ::: "memory");
    __builtin_amdgcn_s_barrier();

    // ---- dense stores: 2 rows per wave, 1 KB dwordx4 each ----
    // Read LDS at swizzled (lane*16)^rs -> elements 4*lane..4*lane+3;
    // store to global at LINEAR lane*16.
#pragma unroll
    for (int q = 0; q < 2; ++q) {
      const int rr = 2 * wv + q;
      const unsigned rs  = (unsigned)((rr & 7) << 4);
      const unsigned off = ((unsigned)(lane * 16)) ^ rs;
      v4f val = *reinterpret_cast<const v4f*>(slotp + rr * 1024 + off);
      float* op = out + (size_t)((t0 + p) * 16 + rr) * CCH + head * D;
      *reinterpret_cast<v4f*>((char*)op + (unsigned)(lane * 16)) = val;
    }

    // newest 4 VMEM = stage(p+2)[2] + stores(p)[2]; guarantees stage(p+1)
    // and stores(p-1) retired while stage(p+2) stays in flight.
    asm volatile("s_waitcnt vmcnt(4)" ::: "memory");
    __builtin_amdgcn_s_barrier();

    cur = cur + 1; if (cur >= 3) cur = 0;
  }
}

extern "C" void kernel_launch(void* const* d_in, const int* in_sizes, int n_in,
                              void* d_out, int out_size, void* d_ws, size_t ws_size,
                              hipStream_t stream) {
  const float* x = (const float*)d_in[0];   // (8,56,56,2048) fp32
  const float* w = (const float*)d_in[1];   // (8,256,256) fp32
  float* out = (float*)d_out;               // (8,56,56,2048) fp32
  short* packed = (short*)d_ws;             // 1 MiB packed bf16 weights

  pack_w<<<256, 256, 0, stream>>>(w, packed);
  grouped_mm<<<NUM_HEADS * SEGS, 512, 0, stream>>>(x, packed, out);
}

// Round 9
// 86.974 us; speedup vs baseline: 1.6860x; 1.0209x over previous
//
#include <hip/hip_runtime.h>
#include <hip/hip_bf16.h>
#include <cstdint>

typedef __attribute__((ext_vector_type(8))) short v8s;   // 8 x bf16 bits (4 VGPRs)
typedef __attribute__((ext_vector_type(4))) float v4f;   // 16B fp32 / MFMA acc

#define NUM_HEADS 8
#define D 256
#define CCH 2048               // channels
#define SEGS 64                // segments (blocks) per head

// float -> bf16 bits, round-to-nearest-even
__device__ __forceinline__ short f2bf(float f) {
  unsigned u = __builtin_bit_cast(unsigned, f);
  u = (u + 0x7FFFu + ((u >> 16) & 1u)) >> 16;
  return (short)u;
}

// ---------------------------------------------------------------------------
// Pack weight (8,256,256) fp32 -> fragment-ordered bf16 in d_ws (1 MiB).
// Unit u = (s*16 + j)*64 + lane within head, 16 B each:
// B[k = s*32 + (lane>>4)*8 + e][n = j*16 + (lane&15)], e = 0..7 — the
// mfma_f32_16x16x32_bf16 B fragment for (kstep s, ntile j).
// ---------------------------------------------------------------------------
__global__ __launch_bounds__(256) void pack_w(const float* __restrict__ w,
                                              short* __restrict__ p) {
  int idx  = blockIdx.x * 256 + threadIdx.x;  // 0..65535
  int lane = idx & 63;
  int j    = (idx >> 6) & 15;
  int s    = (idx >> 10) & 7;
  int head = idx >> 13;
  int n  = j * 16 + (lane & 15);
  int k0 = s * 32 + (lane >> 4) * 8;
  const float* src = w + head * 65536 + k0 * 256 + n;
  v8s v;
#pragma unroll
  for (int e = 0; e < 8; ++e) v[e] = f2bf(src[e * 256]);
  *reinterpret_cast<v8s*>(p + (size_t)idx * 8) = v;
}

// ---------------------------------------------------------------------------
// Main grouped GEMM. 512 blocks (2/CU) x 512 threads (8 waves) = 4 waves/SIMD.
// Block = (head, 24/25-tile segment). Wave wv: ntiles {2wv,2wv+1}, B slice
// register-resident (64 VGPR), loaded once.
//
// ROUND-9 CHANGE — convert once, stage bf16:
// A tiles are reg-staged: global fp32 -> VGPR -> f2bf -> ds_write_b128, so
// each x element is converted ONCE (previously every one of the 8 waves
// converted the whole tile: 8x the VALU) and LDS slots are bf16 (8 KB, ring-3
// = 24 KB; LDS read traffic halved). Inner loop = 8 x {ds_read_b128 -> MFMA
// fragment directly} — near-zero VALU.
//
// A-slot layout: elem k of row r at byte r*512 + ((k/8)*16 ^ ((r&7)<<4)).
// Row stride 512 = 0 mod 128 would make 16 rows bank-alias; XOR'ing row bits
// into the 16B-slot field gives max 2-way aliasing (free). Writer and reader
// use the same formula (both-sides rule).
//
// Pipeline (2-stage regs + ring-3 LDS): period p issues loads for tile p+2
// (full period of slack), converts+writes tile p+1 (loaded last period) into
// slot (p+1)%3, computes tile p from slot p%3. Slot (p+1)%3 was last read in
// period p-2 — two barriers ago. vmcnt(2) after the issue keeps only the
// 2 new loads in flight (retires g_{p+1} + old stores; conservative for
// stores, proven non-critical in rounds 6/8).
// ---------------------------------------------------------------------------
__global__ __launch_bounds__(512, 4) void grouped_mm(const float* __restrict__ x,
                                                     const short* __restrict__ pB,
                                                     float* __restrict__ out) {
  __shared__ alignas(16) char As[3][8192];  // ring: bf16 tiles [row16][512B]
  const int tid  = threadIdx.x;
  const int wv   = tid >> 6;          // wave 0..7 = n-group (ntiles 2wv, 2wv+1)
  const int lane = tid & 63;
  const int head = blockIdx.x >> 6;
  const int seg  = blockIdx.x & 63;
  const int t0   = (seg < 32) ? seg * 25 : 800 + (seg - 32) * 24;
  const int nt   = (seg < 32) ? 25 : 24;

  const int row = lane & 15;          // A-fragment row
  const int kg  = lane >> 4;          // k subgroup

  // ---- persistent B fragments: 2 ntiles x 8 ksteps (64 VGPR) ----
  v8s Bf0[8], Bf1[8];
  {
    const short* pb = pB + (size_t)head * 65536 + (size_t)lane * 8;
#pragma unroll
    for (int s = 0; s < 8; ++s) {
      Bf0[s] = *reinterpret_cast<const v8s*>(pb + (size_t)(s * 16 + 2 * wv)     * 512);
      Bf1[s] = *reinterpret_cast<const v8s*>(pb + (size_t)(s * 16 + 2 * wv + 1) * 512);
    }
  }

  // ---- staging thread coords: thread t covers (srow, 8 consecutive k) ----
  const int srow  = tid >> 5;         // 0..15
  const int skseg = tid & 31;         // 0..31 (k = skseg*8 .. +7)
  const unsigned swoff = (unsigned)(srow * 512)
                       + (((unsigned)(skseg * 16)) ^ ((unsigned)((srow & 7) << 4)));
  const float* xbase = x + (size_t)head * D + (size_t)srow * CCH + skseg * 8;

  // issue global loads for head-local tile t into named regs (32 B/thread)
  auto issue = [&](int t, v4f& g0, v4f& g1) {
    const float* gp = xbase + (size_t)t * 16 * CCH;
    g0 = *reinterpret_cast<const v4f*>(gp);
    g1 = *reinterpret_cast<const v4f*>(gp + 4);
  };
  // convert + write staged regs into ring slot
  auto writeslot = [&](int slot, const v4f& g0, const v4f& g1) {
    v8s wv8;
#pragma unroll
    for (int e = 0; e < 4; ++e) {
      wv8[e]     = f2bf(g0[e]);
      wv8[4 + e] = f2bf(g1[e]);
    }
    *reinterpret_cast<v8s*>(&As[0][0] + slot * 8192 + swoff) = wv8;
  };

  const unsigned rsw = (unsigned)((row & 7) << 4);

  // compute tile p from slot, store
  auto compute = [&](int slot, int p) {
    const char* ar = &As[0][0] + slot * 8192 + row * 512;
    v4f acc0 = (v4f){0.f, 0.f, 0.f, 0.f};
    v4f acc1 = (v4f){0.f, 0.f, 0.f, 0.f};
#pragma unroll
    for (int s = 0; s < 8; ++s) {
      const unsigned off = (((unsigned)((s * 4 + kg) * 16)) ^ rsw);
      v8s af = *reinterpret_cast<const v8s*>(ar + off);
      acc0 = __builtin_amdgcn_mfma_f32_16x16x32_bf16(af, Bf0[s], acc0, 0, 0, 0);
      acc1 = __builtin_amdgcn_mfma_f32_16x16x32_bf16(af, Bf1[s], acc1, 0, 0, 0);
    }
    // C/D layout: col = lane&15, row = kg*4 + r
    float* op = out + (size_t)((t0 + p) * 16 + kg * 4) * CCH
                    + head * D + wv * 32 + row;
#pragma unroll
    for (int r = 0; r < 4; ++r) {
      op[(size_t)r * CCH]      = acc0[r];
      op[(size_t)r * CCH + 16] = acc1[r];
    }
  };

  // ---- prologue: load tiles 0,1; convert tile 0 into slot 0 ----
  v4f A0, A1, B0, B1;                 // two named ping-pong reg sets (rule #20)
  issue(t0 + 0, A0, A1);
  if (nt > 1) issue(t0 + 1, B0, B1);
  asm volatile("s_waitcnt vmcnt(2)" ::: "memory");  // g0 done, g1 in flight
  writeslot(0, A0, A1);
  asm volatile("s_waitcnt lgkmcnt(0)" ::: "memory");
  __builtin_amdgcn_s_barrier();

  // body(p): GI = reg set to issue g_{p+2} into, GC = reg set holding g_{p+1}
#define BODY(p, GI0, GI1, GC0, GC1)                                        \
  {                                                                        \
    const int c = (p) % 3;                                                 \
    int n1 = c + 1; if (n1 >= 3) n1 -= 3;                                  \
    if ((p) + 2 < nt) issue(t0 + (p) + 2, GI0, GI1);                       \
    asm volatile("s_waitcnt vmcnt(2)" ::: "memory");                       \
    if ((p) + 1 < nt) writeslot(n1, GC0, GC1);                             \
    compute(c, (p));                                                       \
    asm volatile("s_waitcnt lgkmcnt(0)" ::: "memory");                     \
    __builtin_amdgcn_s_barrier();                                          \
  }

  for (int p = 0; p < nt; p += 2) {
    BODY(p, A0, A1, B0, B1);                   // even: issue->A, convert B
    if (p + 1 < nt) BODY(p + 1, B0, B1, A0, A1);  // odd: issue->B, convert A
  }
#undef BODY
}

extern "C" void kernel_launch(void* const* d_in, const int* in_sizes, int n_in,
                              void* d_out, int out_size, void* d_ws, size_t ws_size,
                              hipStream_t stream) {
  const float* x = (const float*)d_in[0];   // (8,56,56,2048) fp32
  const float* w = (const float*)d_in[1];   // (8,256,256) fp32
  float* out = (float*)d_out;               // (8,56,56,2048) fp32
  short* packed = (short*)d_ws;             // 1 MiB packed bf16 weights

  pack_w<<<256, 256, 0, stream>>>(w, packed);
  grouped_mm<<<NUM_HEADS * SEGS, 512, 0, stream>>>(x, packed, out);
}